// Round 9
// baseline (123.985 us; speedup 1.0000x reference)
//
#include <hip/hip_runtime.h>
#include <math.h>

#define BDIM 4
#define NDIM 4096
#define MDIM 4096
#define CDIM 128
#define KSEL 32
#define NCELL 64     // 4x4x4 grid, cell 0.25 >= 2*r widened => ball spans <=2 cells/dim
#define CAP 128      // per-wave candidate cap (expected ~30 hits; P(>128) ~ 0)

typedef float v2f __attribute__((ext_vector_type(2)));

// ws layout: pre[7*C] floats | starts[(NCELL+1)*BDIM] ints | pts4[B*M] float4
#define PRE_BYTES (7 * CDIM * 4)                       // 3584
#define STARTS_BYTES ((NCELL + 1) * BDIM * 4)          // 1040
#define PTS4_OFF (PRE_BYTES + STARTS_BYTES)            // 4624 (16B aligned)
#define WS_NEEDED (PTS4_OFF + (size_t)BDIM * MDIM * 16)

// ---------------------------------------------------------------------------
// helpers
// ---------------------------------------------------------------------------
__device__ __forceinline__ float exp2_hw(float x) {   // bare v_exp_f32 (~1 ulp)
    float r;
    asm("v_exp_f32 %0, %1" : "=v"(r) : "v"(x));
    return r;
}

template <int CTRL, int MASK>
__device__ __forceinline__ float dpp_add(float x) {   // VALU-pipe reduction step
    const int r = __builtin_amdgcn_update_dpp(0, __float_as_int(x), CTRL, MASK, 0xF, true);
    return x + __int_as_float(r);
}
#define DPP_QUAD_XOR1 0xB1
#define DPP_QUAD_XOR2 0x4E
#define DPP_ROW_HALF_MIRROR 0x141
#define DPP_ROW_MIRROR      0x140
#define DPP_ROW_BCAST15     0x142
#define DPP_ROW_BCAST31     0x143

// # set bits of mk in lanes strictly below this lane (v_mbcnt_lo+hi)
__device__ __forceinline__ int rank_before(unsigned long long mk) {
    return __builtin_amdgcn_mbcnt_hi((unsigned)(mk >> 32),
                                     __builtin_amdgcn_mbcnt_lo((unsigned)mk, 0));
}

__device__ __forceinline__ int cell_of(float v) {
    int c = (int)(v * 4.0f);
    return c < 0 ? 0 : (c > 3 ? 3 : c);
}

__device__ __forceinline__ v2f splat(float x) { v2f r; r.x = x; r.y = x; return r; }

__device__ __forceinline__ v2f pk_fma(v2f a, v2f b, v2f c) {   // v_pk_fma_f32
    return __builtin_elementwise_fma(a, b, c);
}

// per-lane channel-pair weights (2 channels per lane)
struct LaneW {
    v2f wqa0, wqa1, wqa2;   // (Wq@Wa)*log2e
    v2f nka0, nka1, nka2;   // -(Wk@Wa)*log2e  (pre-negated)
    v2f cav;                // ((bq-bk)@Wa+ba)*log2e
    v2f wd0, wd1, wd2, bdv; // raw Wd rows + bd
};

__device__ __forceinline__ void load_lane_weights(LaneW& P, const float* pre,
                                                  const float* Wd, const float* bd, int lane) {
    const v2f* pre2 = (const v2f*)pre;
    const v2f* wdp  = (const v2f*)Wd;
    const v2f* bdp  = (const v2f*)bd;
    P.wqa0 = pre2[0 * 64 + lane]; P.wqa1 = pre2[1 * 64 + lane]; P.wqa2 = pre2[2 * 64 + lane];
    P.nka0 = pre2[3 * 64 + lane]; P.nka1 = pre2[4 * 64 + lane]; P.nka2 = pre2[5 * 64 + lane];
    P.cav  = pre2[6 * 64 + lane];
    P.wd0 = wdp[0 * 64 + lane]; P.wd1 = wdp[1 * 64 + lane]; P.wd2 = wdp[2 * 64 + lane];
    P.bdv = bdp[lane];
}

// ---------------------------------------------------------------------------
// attn core for ONE anchor, one wave. Phase 1 is software-pipelined: the
// float4 load for step k+1 issues before the ballot-processing of step k
// (loads are independent of cnt; only the dynamic bounds blocked the
// compiler from doing this itself).
// ---------------------------------------------------------------------------
__device__ __forceinline__ float2 attn_core(int w, int lane,
                                            float ax, float ay, float az,
                                            const LaneW& P,
                                            const float* nbb,
                                            const float4* pb,
                                            const int* st,
                                            float4 (*cand)[CAP - KSEL],
                                            float4 (*sel)[KSEL]) {
    const v2f axv = splat(ax), ayv = splat(ay), azv = splat(az);
    const v2f qa = pk_fma(axv, P.wqa0, pk_fma(ayv, P.wqa1, pk_fma(azv, P.wqa2, P.cav)));
    const v2f ad = pk_fma(axv, P.wd0, pk_fma(ayv, P.wd1, pk_fma(azv, P.wd2, P.bdv)));
    const v2f nwd0 = -P.wd0, nwd1 = -P.wd1, nwd2 = -P.wd2;

    constexpr float R2 = (float)(0.12 * 0.12);
    const float RP = 0.1201f;   // widened; 2*RP < 0.25 => <=2 cells/dim always

    const int cx0 = max(0, (int)((ax - RP) * 4.0f)), cx1 = min(3, (int)((ax + RP) * 4.0f));
    const int cy0 = max(0, (int)((ay - RP) * 4.0f)), cy1 = min(3, (int)((ay + RP) * 4.0f));
    const int cz0 = max(0, (int)((az - RP) * 4.0f)), cz1 = min(3, (int)((az + RP) * 4.0f));

    int rs[4], re[4];
    int nr = 0;
    for (int cz = cz0; cz <= cz1; ++cz)
        for (int cy = cy0; cy <= cy1; ++cy) {
            const int crow = (cz * 4 + cy) * 4;
            rs[nr] = st[crow + cx0];
            re[nr] = st[crow + cx1 + 1];
            ++nr;
        }

    // --- phase 1: pipelined binned scan (2-deep: prefetch next step) ---
    int cnt = 0;
    int r0 = 0, base0 = rs[0], cur_rend = 0, cur_i = 0;
    while (r0 < nr && base0 >= re[r0]) { ++r0; if (r0 < nr) base0 = rs[r0]; }
    float4 cur = make_float4(1e30f, 1e30f, 1e30f, 0.0f);
    if (r0 < nr) {
        cur_rend = re[r0];
        cur_i = base0 + lane;
        cur = pb[min(cur_i, cur_rend - 1)];
    }
    while (r0 < nr) {
        // advance cursor & prefetch next step BEFORE processing current
        int r1 = r0, base1 = base0 + 64;
        while (r1 < nr && base1 >= re[r1]) { ++r1; if (r1 < nr) base1 = rs[r1]; }
        float4 nxt = make_float4(1e30f, 1e30f, 1e30f, 0.0f);
        int nxt_i = 0, nxt_rend = 0;
        if (r1 < nr) {
            nxt_rend = re[r1];
            nxt_i = base1 + lane;
            nxt = pb[min(nxt_i, nxt_rend - 1)];
        }
        // process current step (exact no-fma fp32 d2 — matches np ref)
        const float dx = __fsub_rn(ax, cur.x);
        const float dy = __fsub_rn(ay, cur.y);
        const float dz = __fsub_rn(az, cur.z);
        const float d2 = __fadd_rn(__fadd_rn(__fmul_rn(dx, dx), __fmul_rn(dy, dy)),
                                   __fmul_rn(dz, dz));
        const bool in = (cur_i < cur_rend) && (d2 < R2);
        const unsigned long long mk = __ballot(in);
        const int pos = cnt + rank_before(mk);
        if (in && pos < CAP) {
            if (pos < KSEL) sel[w][pos] = cur;
            else            cand[w][pos - KSEL] = cur;
        }
        cnt += __popcll(mk);
        r0 = r1; base0 = base1;
        cur = nxt; cur_i = nxt_i; cur_rend = nxt_rend;
    }

    // --- selection: the K smallest original indices among hits ---
    int eff;
    if (cnt == 0) {
        if (lane == 0) sel[w][0] = make_float4(nbb[0], nbb[1], nbb[2], 0.0f);
        eff = 1;
    } else if (cnt <= KSEL) {
        eff = cnt;                       // sel already holds them, in hit order
    } else if (cnt <= CAP) {
        float4 c0v = make_float4(0, 0, 0, 0), c1v = make_float4(0, 0, 0, 0);
        int i0 = 0x7fffffff, i1 = 0x7fffffff;
        if (lane < cnt) {
            c0v = (lane < KSEL) ? sel[w][lane] : cand[w][lane - KSEL];
            i0 = __float_as_int(c0v.w);
        }
        if (lane + 64 < cnt) {
            c1v = cand[w][lane + 64 - KSEL];
            i1 = __float_as_int(c1v.w);
        }
        int lo = 0, hi = MDIM - 1;   // smallest T with count(idx<=T) >= KSEL
        while (lo < hi) {
            const int mid = (lo + hi) >> 1;
            const int c = __popcll(__ballot(i0 <= mid)) + __popcll(__ballot(i1 <= mid));
            if (c >= KSEL) hi = mid; else lo = mid + 1;
        }
        __builtin_amdgcn_wave_barrier();   // reads above complete before sel rewrite
        const bool k0 = (i0 <= lo);
        const unsigned long long m0 = __ballot(k0);
        if (k0) sel[w][rank_before(m0)] = c0v;
        const int cc0 = __popcll(m0);
        const bool k1 = (i1 <= lo);
        const unsigned long long m1 = __ballot(k1);
        if (k1) sel[w][cc0 + rank_before(m1)] = c1v;
        eff = KSEL;
    } else {
        // overflow fallback (statistically never): ordered full scan, first K
        int c2 = 0;
        for (int base = 0; base < MDIM && c2 < KSEL; base += 64) {
            const int m = base + lane;
            const float* p = nbb + 3 * m;
            const float nx = p[0], ny = p[1], nz = p[2];
            const float dx = __fsub_rn(ax, nx);
            const float dy = __fsub_rn(ay, ny);
            const float dz = __fsub_rn(az, nz);
            const float d2 = __fadd_rn(__fadd_rn(__fmul_rn(dx, dx), __fmul_rn(dy, dy)),
                                       __fmul_rn(dz, dz));
            const bool in = d2 < R2;
            const unsigned long long mk = __ballot(in);
            const int pos = c2 + rank_before(mk);
            if (in && pos < KSEL) sel[w][pos] = make_float4(nx, ny, nz, 0.0f);
            c2 += __popcll(mk);
        }
        eff = KSEL;
    }

    const int eff4 = (eff + 3) & ~3;  // pad with a selected point: idempotent under max
    __builtin_amdgcn_wave_barrier();
    __builtin_amdgcn_s_waitcnt(0);
    if (lane >= eff && lane < eff4) {
        const float4 f = sel[w][0];
        sel[w][lane] = f;
    }
    __builtin_amdgcn_wave_barrier();

    // --- phase 2: packed channel softmax (exp2 domain) + max-accumulate ---
    v2f acc = splat(-1e30f);
    for (int j = 0; j < eff4; j += 4) {
        v2f pr[4];
        float sv[4];
        #pragma unroll
        for (int t = 0; t < 4; ++t) {
            const float4 v = sel[w][j + t];
            const v2f vx = splat(v.x), vy = splat(v.y), vz = splat(v.z);
            const v2f l = pk_fma(vx, P.nka0, pk_fma(vy, P.nka1, pk_fma(vz, P.nka2, qa)));
            v2f e; e.x = exp2_hw(l.x); e.y = exp2_hw(l.y);
            sv[t] = e.x + e.y;
            const v2f d = pk_fma(vx, nwd0, pk_fma(vy, nwd1, pk_fma(vz, nwd2, ad)));
            pr[t] = d * e;   // v_pk_mul_f32
        }
        #pragma unroll
        for (int t = 0; t < 4; ++t) sv[t] = dpp_add<DPP_QUAD_XOR1, 0xF>(sv[t]);
        #pragma unroll
        for (int t = 0; t < 4; ++t) sv[t] = dpp_add<DPP_QUAD_XOR2, 0xF>(sv[t]);
        #pragma unroll
        for (int t = 0; t < 4; ++t) sv[t] = dpp_add<DPP_ROW_HALF_MIRROR, 0xF>(sv[t]);
        #pragma unroll
        for (int t = 0; t < 4; ++t) sv[t] = dpp_add<DPP_ROW_MIRROR, 0xF>(sv[t]);
        #pragma unroll
        for (int t = 0; t < 4; ++t) sv[t] = dpp_add<DPP_ROW_BCAST15, 0xA>(sv[t]);
        #pragma unroll
        for (int t = 0; t < 4; ++t) sv[t] = dpp_add<DPP_ROW_BCAST31, 0xC>(sv[t]);
        #pragma unroll
        for (int t = 0; t < 4; ++t) {
            const float tot = __int_as_float(__builtin_amdgcn_readlane(__float_as_int(sv[t]), 63));
            const v2f iv = splat(__builtin_amdgcn_rcpf(tot));
            acc = __builtin_elementwise_max(acc, pr[t] * iv);   // pk_mul + pk_max
        }
    }

    float2 o; o.x = acc.x; o.y = acc.y;
    return o;
}

// ---------------------------------------------------------------------------
// fp64 folded-weight fold, work item i in [0, 7*128)
// ---------------------------------------------------------------------------
__device__ __forceinline__ void fold_one(int i, const float* Wq, const float* bq,
                                         const float* Wk, const float* bk,
                                         const float* Wa, const float* ba,
                                         float* pre) {
    const double LOG2E = 1.4426950408889634074;
    const int r = i >> 7, c = i & (CDIM - 1);
    if (r < 3) {
        double s0 = 0, s1 = 0, s2 = 0, s3 = 0;
        for (int k = 0; k < CDIM; k += 4) {
            s0 += (double)Wq[r * CDIM + k + 0] * (double)Wa[(k + 0) * CDIM + c];
            s1 += (double)Wq[r * CDIM + k + 1] * (double)Wa[(k + 1) * CDIM + c];
            s2 += (double)Wq[r * CDIM + k + 2] * (double)Wa[(k + 2) * CDIM + c];
            s3 += (double)Wq[r * CDIM + k + 3] * (double)Wa[(k + 3) * CDIM + c];
        }
        pre[r * CDIM + c] = (float)(((s0 + s1) + (s2 + s3)) * LOG2E);
    } else if (r < 6) {
        const int rr = r - 3;
        double s0 = 0, s1 = 0, s2 = 0, s3 = 0;
        for (int k = 0; k < CDIM; k += 4) {
            s0 += (double)Wk[rr * CDIM + k + 0] * (double)Wa[(k + 0) * CDIM + c];
            s1 += (double)Wk[rr * CDIM + k + 1] * (double)Wa[(k + 1) * CDIM + c];
            s2 += (double)Wk[rr * CDIM + k + 2] * (double)Wa[(k + 2) * CDIM + c];
            s3 += (double)Wk[rr * CDIM + k + 3] * (double)Wa[(k + 3) * CDIM + c];
        }
        pre[r * CDIM + c] = (float)(((s0 + s1) + (s2 + s3)) * (-LOG2E));  // negated
    } else {
        double s = (double)ba[c];
        for (int k = 0; k < CDIM; ++k)
            s += ((double)bq[k] - (double)bk[k]) * (double)Wa[k * CDIM + c];
        pre[6 * CDIM + c] = (float)(s * LOG2E);
    }
}

// ---------------------------------------------------------------------------
// Fused setup (R6-proven): blocks 0..3 bin batch b, block 4 folds weights.
// ---------------------------------------------------------------------------
__launch_bounds__(1024)
__global__ void setup_kernel(const float* __restrict__ neighbor,
                             const float* __restrict__ Wq, const float* __restrict__ bq,
                             const float* __restrict__ Wk, const float* __restrict__ bk,
                             const float* __restrict__ Wa, const float* __restrict__ ba,
                             float* __restrict__ pre,
                             int* __restrict__ starts,
                             float4* __restrict__ pts4,
                             const int do_bins) {
    const int blk = blockIdx.x;
    const int t = threadIdx.x;
    if (do_bins && blk < BDIM) {
        __shared__ int cnts[NCELL];
        __shared__ int curs[NCELL];
        if (t < NCELL) cnts[t] = 0;
        __syncthreads();
        const float* nbb = neighbor + (size_t)blk * MDIM * 3;
        float px[4], py[4], pz[4];
        int cell[4];
        #pragma unroll
        for (int k = 0; k < 4; ++k) {
            const int i = t + k * 1024;
            const float x = nbb[3 * i], y = nbb[3 * i + 1], z = nbb[3 * i + 2];
            px[k] = x; py[k] = y; pz[k] = z;
            cell[k] = (cell_of(z) * 4 + cell_of(y)) * 4 + cell_of(x);
            atomicAdd(&cnts[cell[k]], 1);
        }
        __syncthreads();
        if (t < NCELL) {   // wave 0 exclusive scan over 64 cells
            const int v = cnts[t];
            int inc = v;
            #pragma unroll
            for (int off = 1; off < 64; off <<= 1) {
                const int u = __shfl_up(inc, off);
                if (t >= off) inc += u;
            }
            const int excl = inc - v;
            curs[t] = excl;
            starts[blk * (NCELL + 1) + t] = excl;
            if (t == NCELL - 1) starts[blk * (NCELL + 1) + NCELL] = inc;
        }
        __syncthreads();
        #pragma unroll
        for (int k = 0; k < 4; ++k) {
            const int i = t + k * 1024;
            const int slot = atomicAdd(&curs[cell[k]], 1);
            pts4[(size_t)blk * MDIM + slot] = make_float4(px[k], py[k], pz[k], __int_as_float(i));
        }
    } else if (!do_bins || blk == BDIM) {
        if (t < 7 * CDIM) fold_one(t, Wq, bq, Wk, bk, Wa, ba, pre);
    }
}

// ---------------------------------------------------------------------------
// Main kernel: 8 anchors per 256-thread block, 2 sequential per wave
// (amortizes weight loads + halves block tail). Grid 2048.
// ---------------------------------------------------------------------------
__launch_bounds__(256)
__global__ void attn2_kernel(const float* __restrict__ anchor,
                             const float* __restrict__ neighbor,
                             const float* __restrict__ Wd,
                             const float* __restrict__ bd,
                             const float* __restrict__ pre,
                             const float4* __restrict__ pts4,
                             const int* __restrict__ starts,
                             float* __restrict__ out) {
    __shared__ float4 cand[4][CAP - KSEL];
    __shared__ float4 sel[4][KSEL];

    const int b     = blockIdx.x >> 9;          // 512 blocks per batch
    const int nbase = (blockIdx.x & 511) << 3;  // 8 anchors per block
    const int tid   = threadIdx.x;
    const int w     = tid >> 6;
    const int lane  = tid & 63;

    const float* nbb = neighbor + (size_t)b * MDIM * 3;
    const float4* pb = pts4 + (size_t)b * MDIM;
    const int* st = starts + b * (NCELL + 1);

    LaneW P;
    load_lane_weights(P, pre, Wd, bd, lane);

    #pragma unroll
    for (int rep = 0; rep < 2; ++rep) {
        const int n = nbase + rep * 4 + w;
        const float* ap = anchor + ((size_t)b * NDIM + n) * 3;
        const float2 o = attn_core(w, lane, ap[0], ap[1], ap[2], P, nbb, pb, st, cand, sel);
        ((float2*)out)[((size_t)b * NDIM + n) * 64 + lane] = o;
    }
}

// ---------------------------------------------------------------------------
// Fallback (ws too small for bins): full-scan kernel (ordered early-exit).
// ---------------------------------------------------------------------------
__launch_bounds__(256)
__global__ void attn_fallback(const float* __restrict__ anchor,
                              const float* __restrict__ neighbor,
                              const float* __restrict__ Wd,
                              const float* __restrict__ bd,
                              const float* __restrict__ pre,
                              float* __restrict__ out) {
    __shared__ float4 sel[4][KSEL];
    __shared__ int lists[4][KSEL];

    const int b = blockIdx.x >> 10, n0 = (blockIdx.x & 1023) << 2;
    const int tid = threadIdx.x, w = tid >> 6, lane = tid & 63;
    const int n = n0 + w;
    const float* ap = anchor + ((size_t)b * NDIM + n) * 3;
    const float ax = ap[0], ay = ap[1], az = ap[2];
    const float* nbb = neighbor + (size_t)b * MDIM * 3;

    LaneW P;
    load_lane_weights(P, pre, Wd, bd, lane);
    const v2f axv = splat(ax), ayv = splat(ay), azv = splat(az);
    const v2f qa = pk_fma(axv, P.wqa0, pk_fma(ayv, P.wqa1, pk_fma(azv, P.wqa2, P.cav)));
    const v2f ad = pk_fma(axv, P.wd0, pk_fma(ayv, P.wd1, pk_fma(azv, P.wd2, P.bdv)));
    const v2f nwd0 = -P.wd0, nwd1 = -P.wd1, nwd2 = -P.wd2;

    constexpr float R2 = (float)(0.12 * 0.12);
    int cnt = 0;
    for (int base = 0; base < MDIM && cnt < KSEL; base += 64) {
        const int m = base + lane;
        const float* p = nbb + 3 * m;
        const float dx = __fsub_rn(ax, p[0]);
        const float dy = __fsub_rn(ay, p[1]);
        const float dz = __fsub_rn(az, p[2]);
        const float d2 = __fadd_rn(__fadd_rn(__fmul_rn(dx, dx), __fmul_rn(dy, dy)),
                                   __fmul_rn(dz, dz));
        const bool in = d2 < R2;
        const unsigned long long mk = __ballot(in);
        const int pos = cnt + rank_before(mk);
        if (in && pos < KSEL) lists[w][pos] = m;
        cnt += __popcll(mk);
    }
    int eff = cnt < KSEL ? cnt : KSEL;
    if (cnt == 0) { if (lane == 0) lists[w][0] = 0; eff = 1; }
    const int eff4 = (eff + 3) & ~3;
    if (lane == 0) for (int j = eff; j < eff4; ++j) lists[w][j] = lists[w][0];
    __builtin_amdgcn_wave_barrier();
    if (lane < eff4) {
        const float* p = nbb + 3 * lists[w][lane];
        sel[w][lane] = make_float4(p[0], p[1], p[2], 0.f);
    }
    __builtin_amdgcn_wave_barrier();

    v2f acc = splat(-1e30f);
    for (int j = 0; j < eff4; j += 4) {
        v2f pr[4]; float sv[4];
        #pragma unroll
        for (int t = 0; t < 4; ++t) {
            const float4 v = sel[w][j + t];
            const v2f vx = splat(v.x), vy = splat(v.y), vz = splat(v.z);
            const v2f l = pk_fma(vx, P.nka0, pk_fma(vy, P.nka1, pk_fma(vz, P.nka2, qa)));
            v2f e; e.x = exp2_hw(l.x); e.y = exp2_hw(l.y);
            sv[t] = e.x + e.y;
            const v2f d = pk_fma(vx, nwd0, pk_fma(vy, nwd1, pk_fma(vz, nwd2, ad)));
            pr[t] = d * e;
        }
        #pragma unroll
        for (int t = 0; t < 4; ++t) sv[t] = dpp_add<DPP_QUAD_XOR1, 0xF>(sv[t]);
        #pragma unroll
        for (int t = 0; t < 4; ++t) sv[t] = dpp_add<DPP_QUAD_XOR2, 0xF>(sv[t]);
        #pragma unroll
        for (int t = 0; t < 4; ++t) sv[t] = dpp_add<DPP_ROW_HALF_MIRROR, 0xF>(sv[t]);
        #pragma unroll
        for (int t = 0; t < 4; ++t) sv[t] = dpp_add<DPP_ROW_MIRROR, 0xF>(sv[t]);
        #pragma unroll
        for (int t = 0; t < 4; ++t) sv[t] = dpp_add<DPP_ROW_BCAST15, 0xA>(sv[t]);
        #pragma unroll
        for (int t = 0; t < 4; ++t) sv[t] = dpp_add<DPP_ROW_BCAST31, 0xC>(sv[t]);
        #pragma unroll
        for (int t = 0; t < 4; ++t) {
            const float tot = __int_as_float(__builtin_amdgcn_readlane(__float_as_int(sv[t]), 63));
            const v2f iv = splat(__builtin_amdgcn_rcpf(tot));
            acc = __builtin_elementwise_max(acc, pr[t] * iv);
        }
    }
    float2 o; o.x = acc.x; o.y = acc.y;
    ((float2*)out)[((size_t)b * NDIM + n) * 64 + lane] = o;
}

extern "C" void kernel_launch(void* const* d_in, const int* in_sizes, int n_in,
                              void* d_out, int out_size, void* d_ws, size_t ws_size,
                              hipStream_t stream) {
    const float* anchor   = (const float*)d_in[0];
    const float* neighbor = (const float*)d_in[1];
    const float* Wq = (const float*)d_in[2];
    const float* bq = (const float*)d_in[3];
    const float* Wk = (const float*)d_in[4];
    const float* bk = (const float*)d_in[5];
    const float* Wd = (const float*)d_in[6];
    const float* bd = (const float*)d_in[7];
    const float* Wa = (const float*)d_in[8];
    const float* ba = (const float*)d_in[9];
    float* out = (float*)d_out;

    float* pre   = (float*)d_ws;
    int* starts  = (int*)((char*)d_ws + PRE_BYTES);
    float4* pts4 = (float4*)((char*)d_ws + PTS4_OFF);

    if (ws_size >= WS_NEEDED) {
        setup_kernel<<<dim3(BDIM + 1), dim3(1024), 0, stream>>>(
            neighbor, Wq, bq, Wk, bk, Wa, ba, pre, starts, pts4, 1);
        attn2_kernel<<<dim3(BDIM * NDIM / 8), dim3(256), 0, stream>>>(
            anchor, neighbor, Wd, bd, pre, pts4, starts, out);
    } else {
        setup_kernel<<<dim3(1), dim3(1024), 0, stream>>>(
            neighbor, Wq, bq, Wk, bk, Wa, ba, pre, starts, pts4, 0);
        attn_fallback<<<dim3(BDIM * NDIM / 4), dim3(256), 0, stream>>>(
            anchor, neighbor, Wd, bd, pre, out);
    }
}

// Round 10
// 115.823 us; speedup vs baseline: 1.0705x; 1.0705x over previous
//
#include <hip/hip_runtime.h>
#include <math.h>

#define BDIM 4
#define NDIM 4096
#define MDIM 4096
#define CDIM 128
#define KSEL 32
#define NCELL 64     // 4x4x4 grid, cell 0.25 >= 2*r widened => ball spans <=2 cells/dim
#define CAP 128      // per-wave candidate cap (expected ~30 hits; P(>128) ~ 0)

typedef float v2f __attribute__((ext_vector_type(2)));

// ws layout: pre[7*C] floats | starts[(NCELL+1)*BDIM] ints | pts4[B*M] float4
#define PRE_BYTES (7 * CDIM * 4)                       // 3584
#define STARTS_BYTES ((NCELL + 1) * BDIM * 4)          // 1040
#define PTS4_OFF (PRE_BYTES + STARTS_BYTES)            // 4624 (16B aligned)
#define WS_NEEDED (PTS4_OFF + (size_t)BDIM * MDIM * 16)

// ---------------------------------------------------------------------------
// helpers
// ---------------------------------------------------------------------------
__device__ __forceinline__ float exp2_hw(float x) {   // bare v_exp_f32 (~1 ulp)
    float r;
    asm("v_exp_f32 %0, %1" : "=v"(r) : "v"(x));
    return r;
}

template <int CTRL, int MASK>
__device__ __forceinline__ float dpp_add(float x) {   // VALU-pipe reduction step
    const int r = __builtin_amdgcn_update_dpp(0, __float_as_int(x), CTRL, MASK, 0xF, true);
    return x + __int_as_float(r);
}
#define DPP_QUAD_XOR1 0xB1
#define DPP_QUAD_XOR2 0x4E
#define DPP_ROW_HALF_MIRROR 0x141
#define DPP_ROW_MIRROR      0x140
#define DPP_ROW_BCAST15     0x142
#define DPP_ROW_BCAST31     0x143

// # set bits of mk in lanes strictly below this lane (v_mbcnt_lo+hi)
__device__ __forceinline__ int rank_before(unsigned long long mk) {
    return __builtin_amdgcn_mbcnt_hi((unsigned)(mk >> 32),
                                     __builtin_amdgcn_mbcnt_lo((unsigned)mk, 0));
}

__device__ __forceinline__ int cell_of(float v) {
    int c = (int)(v * 4.0f);
    return c < 0 ? 0 : (c > 3 ? 3 : c);
}

__device__ __forceinline__ v2f splat(float x) { v2f r; r.x = x; r.y = x; return r; }

// packed fma: lowers to v_pk_fma_f32 (full-rate, 2 fp32 FMA / inst)
__device__ __forceinline__ v2f pk_fma(v2f a, v2f b, v2f c) {
    return __builtin_elementwise_fma(a, b, c);
}

// per-lane channel-pair weights (2 channels per lane)
struct LaneW {
    v2f wqa0, wqa1, wqa2;   // (Wq@Wa)*log2e
    v2f nka0, nka1, nka2;   // -(Wk@Wa)*log2e  (pre-negated)
    v2f cav;                // ((bq-bk)@Wa+ba)*log2e
    v2f wd0, wd1, wd2, bdv; // raw Wd rows + bd
};

__device__ __forceinline__ void load_lane_weights(LaneW& P, const float* pre,
                                                  const float* Wd, const float* bd, int lane) {
    const v2f* pre2 = (const v2f*)pre;
    const v2f* wdp  = (const v2f*)Wd;
    const v2f* bdp  = (const v2f*)bd;
    P.wqa0 = pre2[0 * 64 + lane]; P.wqa1 = pre2[1 * 64 + lane]; P.wqa2 = pre2[2 * 64 + lane];
    P.nka0 = pre2[3 * 64 + lane]; P.nka1 = pre2[4 * 64 + lane]; P.nka2 = pre2[5 * 64 + lane];
    P.cav  = pre2[6 * 64 + lane];
    P.wd0 = wdp[0 * 64 + lane]; P.wd1 = wdp[1 * 64 + lane]; P.wd2 = wdp[2 * 64 + lane];
    P.bdv = bdp[lane];
}

// ---------------------------------------------------------------------------
// fp64 folded-weight fold, work item i in [0, 7*128)
// ---------------------------------------------------------------------------
__device__ __forceinline__ void fold_one(int i, const float* Wq, const float* bq,
                                         const float* Wk, const float* bk,
                                         const float* Wa, const float* ba,
                                         float* pre) {
    const double LOG2E = 1.4426950408889634074;
    const int r = i >> 7, c = i & (CDIM - 1);
    if (r < 3) {
        double s0 = 0, s1 = 0, s2 = 0, s3 = 0;
        for (int k = 0; k < CDIM; k += 4) {
            s0 += (double)Wq[r * CDIM + k + 0] * (double)Wa[(k + 0) * CDIM + c];
            s1 += (double)Wq[r * CDIM + k + 1] * (double)Wa[(k + 1) * CDIM + c];
            s2 += (double)Wq[r * CDIM + k + 2] * (double)Wa[(k + 2) * CDIM + c];
            s3 += (double)Wq[r * CDIM + k + 3] * (double)Wa[(k + 3) * CDIM + c];
        }
        pre[r * CDIM + c] = (float)(((s0 + s1) + (s2 + s3)) * LOG2E);
    } else if (r < 6) {
        const int rr = r - 3;
        double s0 = 0, s1 = 0, s2 = 0, s3 = 0;
        for (int k = 0; k < CDIM; k += 4) {
            s0 += (double)Wk[rr * CDIM + k + 0] * (double)Wa[(k + 0) * CDIM + c];
            s1 += (double)Wk[rr * CDIM + k + 1] * (double)Wa[(k + 1) * CDIM + c];
            s2 += (double)Wk[rr * CDIM + k + 2] * (double)Wa[(k + 2) * CDIM + c];
            s3 += (double)Wk[rr * CDIM + k + 3] * (double)Wa[(k + 3) * CDIM + c];
        }
        pre[r * CDIM + c] = (float)(((s0 + s1) + (s2 + s3)) * (-LOG2E));  // negated
    } else {
        double s = (double)ba[c];
        for (int k = 0; k < CDIM; ++k)
            s += ((double)bq[k] - (double)bk[k]) * (double)Wa[k * CDIM + c];
        pre[6 * CDIM + c] = (float)(s * LOG2E);
    }
}

// ---------------------------------------------------------------------------
// Fused setup (R6-proven): blocks 0..3 bin batch b, block 4 folds weights.
// ---------------------------------------------------------------------------
__launch_bounds__(1024)
__global__ void setup_kernel(const float* __restrict__ neighbor,
                             const float* __restrict__ Wq, const float* __restrict__ bq,
                             const float* __restrict__ Wk, const float* __restrict__ bk,
                             const float* __restrict__ Wa, const float* __restrict__ ba,
                             float* __restrict__ pre,
                             int* __restrict__ starts,
                             float4* __restrict__ pts4,
                             const int do_bins) {
    const int blk = blockIdx.x;
    const int t = threadIdx.x;
    if (do_bins && blk < BDIM) {
        __shared__ int cnts[NCELL];
        __shared__ int curs[NCELL];
        if (t < NCELL) cnts[t] = 0;
        __syncthreads();
        const float* nbb = neighbor + (size_t)blk * MDIM * 3;
        float px[4], py[4], pz[4];
        int cell[4];
        #pragma unroll
        for (int k = 0; k < 4; ++k) {
            const int i = t + k * 1024;
            const float x = nbb[3 * i], y = nbb[3 * i + 1], z = nbb[3 * i + 2];
            px[k] = x; py[k] = y; pz[k] = z;
            cell[k] = (cell_of(z) * 4 + cell_of(y)) * 4 + cell_of(x);
            atomicAdd(&cnts[cell[k]], 1);
        }
        __syncthreads();
        if (t < NCELL) {   // wave 0 exclusive scan over 64 cells
            const int v = cnts[t];
            int inc = v;
            #pragma unroll
            for (int off = 1; off < 64; off <<= 1) {
                const int u = __shfl_up(inc, off);
                if (t >= off) inc += u;
            }
            const int excl = inc - v;
            curs[t] = excl;
            starts[blk * (NCELL + 1) + t] = excl;
            if (t == NCELL - 1) starts[blk * (NCELL + 1) + NCELL] = inc;
        }
        __syncthreads();
        #pragma unroll
        for (int k = 0; k < 4; ++k) {
            const int i = t + k * 1024;
            const int slot = atomicAdd(&curs[cell[k]], 1);
            pts4[(size_t)blk * MDIM + slot] = make_float4(px[k], py[k], pz[k], __int_as_float(i));
        }
    } else if (!do_bins || blk == BDIM) {
        if (t < 7 * CDIM) fold_one(t, Wq, bq, Wk, bk, Wa, ba, pre);
    }
}

// ---------------------------------------------------------------------------
// Main kernel (R8-proven best): 1 wave per anchor, 4 waves / 256-thread block,
// grid 4096 (max TLP — R9 showed coarsening/pipelining regress).
// Phase 1: binned candidate scan; hits pos<KSEL written DIRECTLY to sel,
//          overflow to cand. Exact no-fma fp32 d2 test (matches np ref).
// Selection (cnt>K): 12-iter ballot binary-search on index threshold.
// Phase 2: packed fp32 (v_pk_fma/mul/max), bare v_exp_f32, DPP wave64
//          softmax denominator.
// ---------------------------------------------------------------------------
__launch_bounds__(256)
__global__ void attn2_kernel(const float* __restrict__ anchor,
                             const float* __restrict__ neighbor,
                             const float* __restrict__ Wd,
                             const float* __restrict__ bd,
                             const float* __restrict__ pre,
                             const float4* __restrict__ pts4,
                             const int* __restrict__ starts,
                             float* __restrict__ out) {
    __shared__ float4 cand[4][CAP - KSEL];
    __shared__ float4 sel[4][KSEL];

    const int b    = blockIdx.x >> 10;
    const int n0   = (blockIdx.x & 1023) << 2;
    const int tid  = threadIdx.x;
    const int w    = tid >> 6;
    const int lane = tid & 63;

    const int n = n0 + w;
    const float* ap = anchor + ((size_t)b * NDIM + n) * 3;
    const float ax = ap[0], ay = ap[1], az = ap[2];
    const float* nbb = neighbor + (size_t)b * MDIM * 3;

    LaneW P;
    load_lane_weights(P, pre, Wd, bd, lane);

    const v2f axv = splat(ax), ayv = splat(ay), azv = splat(az);
    const v2f qa = pk_fma(axv, P.wqa0, pk_fma(ayv, P.wqa1, pk_fma(azv, P.wqa2, P.cav)));
    const v2f ad = pk_fma(axv, P.wd0, pk_fma(ayv, P.wd1, pk_fma(azv, P.wd2, P.bdv)));
    const v2f nwd0 = -P.wd0, nwd1 = -P.wd1, nwd2 = -P.wd2;

    // --- phase 1: binned candidate collection ---
    constexpr float R2 = (float)(0.12 * 0.12);
    const float RP = 0.1201f;   // widened; 2*RP < 0.25 => <=2 cells/dim always

    const int cx0 = max(0, (int)((ax - RP) * 4.0f)), cx1 = min(3, (int)((ax + RP) * 4.0f));
    const int cy0 = max(0, (int)((ay - RP) * 4.0f)), cy1 = min(3, (int)((ay + RP) * 4.0f));
    const int cz0 = max(0, (int)((az - RP) * 4.0f)), cz1 = min(3, (int)((az + RP) * 4.0f));

    const float4* pb = pts4 + (size_t)b * MDIM;
    const int* st = starts + b * (NCELL + 1);

    int rs[4], re[4];
    int nr = 0;
    for (int cz = cz0; cz <= cz1; ++cz)
        for (int cy = cy0; cy <= cy1; ++cy) {
            const int crow = (cz * 4 + cy) * 4;
            rs[nr] = st[crow + cx0];
            re[nr] = st[crow + cx1 + 1];
            ++nr;
        }

    int cnt = 0;
    for (int r = 0; r < nr; ++r) {
        const int rend = re[r];
        for (int base = rs[r]; base < rend; base += 64) {
            const int i = base + lane;
            const float4 p = pb[min(i, rend - 1)];   // clamped load; validity via flag
            const float dx = __fsub_rn(ax, p.x);
            const float dy = __fsub_rn(ay, p.y);
            const float dz = __fsub_rn(az, p.z);
            const float d2 = __fadd_rn(__fadd_rn(__fmul_rn(dx, dx), __fmul_rn(dy, dy)),
                                       __fmul_rn(dz, dz));
            const bool in = (i < rend) && (d2 < R2);
            const unsigned long long mk = __ballot(in);
            const int pos = cnt + rank_before(mk);
            if (in && pos < CAP) {
                if (pos < KSEL) sel[w][pos] = p;
                else            cand[w][pos - KSEL] = p;
            }
            cnt += __popcll(mk);
        }
    }

    // --- selection: the K smallest original indices among hits ---
    int eff;
    if (cnt == 0) {
        if (lane == 0) sel[w][0] = make_float4(nbb[0], nbb[1], nbb[2], 0.0f);
        eff = 1;
    } else if (cnt <= KSEL) {
        eff = cnt;                       // sel already holds them, in hit order
    } else if (cnt <= CAP) {
        // gather hit h for this lane: h<KSEL -> sel[h], else cand[h-KSEL]
        float4 c0v = make_float4(0, 0, 0, 0), c1v = make_float4(0, 0, 0, 0);
        int i0 = 0x7fffffff, i1 = 0x7fffffff;
        if (lane < cnt) {
            c0v = (lane < KSEL) ? sel[w][lane] : cand[w][lane - KSEL];
            i0 = __float_as_int(c0v.w);
        }
        if (lane + 64 < cnt) {
            c1v = cand[w][lane + 64 - KSEL];
            i1 = __float_as_int(c1v.w);
        }
        int lo = 0, hi = MDIM - 1;   // smallest T with count(idx<=T) >= KSEL
        while (lo < hi) {
            const int mid = (lo + hi) >> 1;
            const int c = __popcll(__ballot(i0 <= mid)) + __popcll(__ballot(i1 <= mid));
            if (c >= KSEL) hi = mid; else lo = mid + 1;
        }
        __builtin_amdgcn_wave_barrier();   // reads above complete before sel rewrite
        const bool k0 = (i0 <= lo);
        const unsigned long long m0 = __ballot(k0);
        if (k0) sel[w][rank_before(m0)] = c0v;
        const int cc0 = __popcll(m0);
        const bool k1 = (i1 <= lo);
        const unsigned long long m1 = __ballot(k1);
        if (k1) sel[w][cc0 + rank_before(m1)] = c1v;
        eff = KSEL;
    } else {
        // overflow fallback (statistically never): ordered full scan, first K
        int c2 = 0;
        for (int base = 0; base < MDIM && c2 < KSEL; base += 64) {
            const int m = base + lane;
            const float* p = nbb + 3 * m;
            const float nx = p[0], ny = p[1], nz = p[2];
            const float dx = __fsub_rn(ax, nx);
            const float dy = __fsub_rn(ay, ny);
            const float dz = __fsub_rn(az, nz);
            const float d2 = __fadd_rn(__fadd_rn(__fmul_rn(dx, dx), __fmul_rn(dy, dy)),
                                       __fmul_rn(dz, dz));
            const bool in = d2 < R2;
            const unsigned long long mk = __ballot(in);
            const int pos = c2 + rank_before(mk);
            if (in && pos < KSEL) sel[w][pos] = make_float4(nx, ny, nz, 0.0f);
            c2 += __popcll(mk);
        }
        eff = KSEL;
    }

    const int eff4 = (eff + 3) & ~3;  // pad with a selected point: idempotent under max
    __builtin_amdgcn_wave_barrier();
    __builtin_amdgcn_s_waitcnt(0);
    if (lane >= eff && lane < eff4) {
        const float4 f = sel[w][0];
        sel[w][lane] = f;
    }
    __builtin_amdgcn_wave_barrier();

    // --- phase 2: packed channel softmax (exp2 domain) + max-accumulate ---
    v2f acc = splat(-1e30f);
    for (int j = 0; j < eff4; j += 4) {
        v2f pr[4];
        float sv[4];
        #pragma unroll
        for (int t = 0; t < 4; ++t) {
            const float4 v = sel[w][j + t];
            const v2f vx = splat(v.x), vy = splat(v.y), vz = splat(v.z);
            const v2f l = pk_fma(vx, P.nka0, pk_fma(vy, P.nka1, pk_fma(vz, P.nka2, qa)));
            v2f e; e.x = exp2_hw(l.x); e.y = exp2_hw(l.y);
            sv[t] = e.x + e.y;
            const v2f d = pk_fma(vx, nwd0, pk_fma(vy, nwd1, pk_fma(vz, nwd2, ad)));
            pr[t] = d * e;   // v_pk_mul_f32
        }
        #pragma unroll
        for (int t = 0; t < 4; ++t) sv[t] = dpp_add<DPP_QUAD_XOR1, 0xF>(sv[t]);
        #pragma unroll
        for (int t = 0; t < 4; ++t) sv[t] = dpp_add<DPP_QUAD_XOR2, 0xF>(sv[t]);
        #pragma unroll
        for (int t = 0; t < 4; ++t) sv[t] = dpp_add<DPP_ROW_HALF_MIRROR, 0xF>(sv[t]);
        #pragma unroll
        for (int t = 0; t < 4; ++t) sv[t] = dpp_add<DPP_ROW_MIRROR, 0xF>(sv[t]);
        #pragma unroll
        for (int t = 0; t < 4; ++t) sv[t] = dpp_add<DPP_ROW_BCAST15, 0xA>(sv[t]);
        #pragma unroll
        for (int t = 0; t < 4; ++t) sv[t] = dpp_add<DPP_ROW_BCAST31, 0xC>(sv[t]);
        #pragma unroll
        for (int t = 0; t < 4; ++t) {
            const float tot = __int_as_float(__builtin_amdgcn_readlane(__float_as_int(sv[t]), 63));
            const v2f iv = splat(__builtin_amdgcn_rcpf(tot));
            acc = __builtin_elementwise_max(acc, pr[t] * iv);   // pk_mul + pk_max
        }
    }

    float2 o; o.x = acc.x; o.y = acc.y;
    ((float2*)out)[((size_t)b * NDIM + n) * 64 + lane] = o;
}

// ---------------------------------------------------------------------------
// Fallback (ws too small for bins): full-scan kernel (ordered early-exit).
// ---------------------------------------------------------------------------
__launch_bounds__(256)
__global__ void attn_fallback(const float* __restrict__ anchor,
                              const float* __restrict__ neighbor,
                              const float* __restrict__ Wd,
                              const float* __restrict__ bd,
                              const float* __restrict__ pre,
                              float* __restrict__ out) {
    __shared__ float4 sel[4][KSEL];
    __shared__ int lists[4][KSEL];

    const int b = blockIdx.x >> 10, n0 = (blockIdx.x & 1023) << 2;
    const int tid = threadIdx.x, w = tid >> 6, lane = tid & 63;
    const int n = n0 + w;
    const float* ap = anchor + ((size_t)b * NDIM + n) * 3;
    const float ax = ap[0], ay = ap[1], az = ap[2];
    const float* nbb = neighbor + (size_t)b * MDIM * 3;

    LaneW P;
    load_lane_weights(P, pre, Wd, bd, lane);
    const v2f axv = splat(ax), ayv = splat(ay), azv = splat(az);
    const v2f qa = pk_fma(axv, P.wqa0, pk_fma(ayv, P.wqa1, pk_fma(azv, P.wqa2, P.cav)));
    const v2f ad = pk_fma(axv, P.wd0, pk_fma(ayv, P.wd1, pk_fma(azv, P.wd2, P.bdv)));
    const v2f nwd0 = -P.wd0, nwd1 = -P.wd1, nwd2 = -P.wd2;

    constexpr float R2 = (float)(0.12 * 0.12);
    int cnt = 0;
    for (int base = 0; base < MDIM && cnt < KSEL; base += 64) {
        const int m = base + lane;
        const float* p = nbb + 3 * m;
        const float dx = __fsub_rn(ax, p[0]);
        const float dy = __fsub_rn(ay, p[1]);
        const float dz = __fsub_rn(az, p[2]);
        const float d2 = __fadd_rn(__fadd_rn(__fmul_rn(dx, dx), __fmul_rn(dy, dy)),
                                   __fmul_rn(dz, dz));
        const bool in = d2 < R2;
        const unsigned long long mk = __ballot(in);
        const int pos = cnt + rank_before(mk);
        if (in && pos < KSEL) lists[w][pos] = m;
        cnt += __popcll(mk);
    }
    int eff = cnt < KSEL ? cnt : KSEL;
    if (cnt == 0) { if (lane == 0) lists[w][0] = 0; eff = 1; }
    const int eff4 = (eff + 3) & ~3;
    if (lane == 0) for (int j = eff; j < eff4; ++j) lists[w][j] = lists[w][0];
    __builtin_amdgcn_wave_barrier();
    if (lane < eff4) {
        const float* p = nbb + 3 * lists[w][lane];
        sel[w][lane] = make_float4(p[0], p[1], p[2], 0.f);
    }
    __builtin_amdgcn_wave_barrier();

    v2f acc = splat(-1e30f);
    for (int j = 0; j < eff4; j += 4) {
        v2f pr[4]; float sv[4];
        #pragma unroll
        for (int t = 0; t < 4; ++t) {
            const float4 v = sel[w][j + t];
            const v2f vx = splat(v.x), vy = splat(v.y), vz = splat(v.z);
            const v2f l = pk_fma(vx, P.nka0, pk_fma(vy, P.nka1, pk_fma(vz, P.nka2, qa)));
            v2f e; e.x = exp2_hw(l.x); e.y = exp2_hw(l.y);
            sv[t] = e.x + e.y;
            const v2f d = pk_fma(vx, nwd0, pk_fma(vy, nwd1, pk_fma(vz, nwd2, ad)));
            pr[t] = d * e;
        }
        #pragma unroll
        for (int t = 0; t < 4; ++t) sv[t] = dpp_add<DPP_QUAD_XOR1, 0xF>(sv[t]);
        #pragma unroll
        for (int t = 0; t < 4; ++t) sv[t] = dpp_add<DPP_QUAD_XOR2, 0xF>(sv[t]);
        #pragma unroll
        for (int t = 0; t < 4; ++t) sv[t] = dpp_add<DPP_ROW_HALF_MIRROR, 0xF>(sv[t]);
        #pragma unroll
        for (int t = 0; t < 4; ++t) sv[t] = dpp_add<DPP_ROW_MIRROR, 0xF>(sv[t]);
        #pragma unroll
        for (int t = 0; t < 4; ++t) sv[t] = dpp_add<DPP_ROW_BCAST15, 0xA>(sv[t]);
        #pragma unroll
        for (int t = 0; t < 4; ++t) sv[t] = dpp_add<DPP_ROW_BCAST31, 0xC>(sv[t]);
        #pragma unroll
        for (int t = 0; t < 4; ++t) {
            const float tot = __int_as_float(__builtin_amdgcn_readlane(__float_as_int(sv[t]), 63));
            const v2f iv = splat(__builtin_amdgcn_rcpf(tot));
            acc = __builtin_elementwise_max(acc, pr[t] * iv);
        }
    }
    float2 o; o.x = acc.x; o.y = acc.y;
    ((float2*)out)[((size_t)b * NDIM + n) * 64 + lane] = o;
}

extern "C" void kernel_launch(void* const* d_in, const int* in_sizes, int n_in,
                              void* d_out, int out_size, void* d_ws, size_t ws_size,
                              hipStream_t stream) {
    const float* anchor   = (const float*)d_in[0];
    const float* neighbor = (const float*)d_in[1];
    const float* Wq = (const float*)d_in[2];
    const float* bq = (const float*)d_in[3];
    const float* Wk = (const float*)d_in[4];
    const float* bk = (const float*)d_in[5];
    const float* Wd = (const float*)d_in[6];
    const float* bd = (const float*)d_in[7];
    const float* Wa = (const float*)d_in[8];
    const float* ba = (const float*)d_in[9];
    float* out = (float*)d_out;

    float* pre   = (float*)d_ws;
    int* starts  = (int*)((char*)d_ws + PRE_BYTES);
    float4* pts4 = (float4*)((char*)d_ws + PTS4_OFF);

    if (ws_size >= WS_NEEDED) {
        setup_kernel<<<dim3(BDIM + 1), dim3(1024), 0, stream>>>(
            neighbor, Wq, bq, Wk, bk, Wa, ba, pre, starts, pts4, 1);
        attn2_kernel<<<dim3(BDIM * NDIM / 4), dim3(256), 0, stream>>>(
            anchor, neighbor, Wd, bd, pre, pts4, starts, out);
    } else {
        setup_kernel<<<dim3(1), dim3(1024), 0, stream>>>(
            neighbor, Wq, bq, Wk, bk, Wa, ba, pre, starts, pts4, 0);
        attn_fallback<<<dim3(BDIM * NDIM / 4), dim3(256), 0, stream>>>(
            anchor, neighbor, Wd, bd, pre, out);
    }
}